// Round 17
// baseline (60.674 us; speedup 1.0000x reference)
//
#include <hip/hip_runtime.h>

// FlatColorShader, two-kernel edition: (A) LDS-sliced scan -> u16 RGB565 per
// pixel; (B) pure-stream decode u16 -> f32x3.
//
// Evidence trail:
//  R1-R5:  VMEM random gather ~5.7 cy/px/CU (L1-miss handling), insensitive to
//          instr shape -> LDS gather path.
//  R6:     spills -> launch_bounds. R9/R12: intra-block overlap structurally
//          limited (stores+stage share in-order per-wave vmcnt).
//  R13/R15: best fused config: 2 blocks/CU, 5 x 80KB slices, parity stagger,
//          masked scan (R14: de-masking regresses) = 47.1us.
//  R16:    in-block VMEM mix regresses (52.6): gathers share vmcnt+L1 with
//          stage; VMEM path adds nothing co-located with LDS path.
//  R17:    the 100 MB f32 store stream runs poorly inside 16-wave barrier
//          blocks (phase-serialized tail), while the harness fill kernel
//          sustains 7 TB/s from small streaming blocks. Split: A stores 2B/px
//          RGB565 (store phase /6, no decode VALU); B = fill-shaped streaming
//          decode (16.8 MB in, 100.7 MB out). +33.6 MB traffic, bet: phase
//          decoupling wins more. Fallback to fused epilogue if ws too small.

#define SLICE_E 40960        // u16 entries per slice = 80 KiB
#define NSLICE  5            // ceil(200000 / 40960)
#define TPB     1024
#define PXT     16
#define PPB     (TPB * PXT)  // 16384 px per block

typedef unsigned u32;
typedef unsigned short u16;

__global__ void face_avg_565_kernel(const float* __restrict__ verts,
                                    const int*   __restrict__ faces,
                                    u16*         __restrict__ tab,
                                    int F, int Fpad) {
    int f = blockIdx.x * blockDim.x + threadIdx.x;
    if (f >= Fpad) return;
    u32 packed = 0u;
    if (f < F) {
        int i0 = faces[3*f+0], i1 = faces[3*f+1], i2 = faces[3*f+2];
        const float s = 1.0f / 3.0f;
        float r = (verts[3*i0+0] + verts[3*i1+0] + verts[3*i2+0]) * s;
        float g = (verts[3*i0+1] + verts[3*i1+1] + verts[3*i2+1]) * s;
        float b = (verts[3*i0+2] + verts[3*i1+2] + verts[3*i2+2]) * s;
        u32 r5 = (u32)__float2int_rn(r * 31.0f);
        u32 g6 = (u32)__float2int_rn(g * 63.0f);
        u32 b5 = (u32)__float2int_rn(b * 31.0f);
        packed = (r5 << 11) | (g6 << 5) | b5;
    }
    tab[f] = (u16)packed;
}

// Kernel A: scan. If cbuf != nullptr, store u16 colors there (split mode);
// else decode and store f32 to out (fused fallback).
__global__ __launch_bounds__(TPB, 8)
void shade_kernel(const int* __restrict__ pix,
                  const u16* __restrict__ tab,
                  u16*       __restrict__ cbuf,
                  float*     __restrict__ out,
                  int n_pix) {
    __shared__ u16 buf[SLICE_E];        // 80 KiB -> 2 independent blocks/CU
    const int tid  = threadIdx.x;
    const int lane = tid & 63;
    const int wave = tid >> 6;          // 0..15
    const int base = blockIdx.x * PPB;
    const int off  = (blockIdx.x & 1) ? 2 : 0;   // parity slice stagger

    auto stage = [&](int ss) {
        const u16* g = tab + (size_t)ss * SLICE_E + wave * 2560 + lane * 8;
#pragma unroll
        for (int j = 0; j < 5; ++j) {
            __builtin_amdgcn_global_load_lds(
                (const __attribute__((address_space(1))) u32*)(g + j * 512),
                (__attribute__((address_space(3))) u32*)(&buf[wave * 2560 + j * 512]),
                16, 0, 0);
        }
    };

    stage(off);                         // first slice in flight during id load

    int id[PXT];
#pragma unroll
    for (int k = 0; k < 4; ++k) {
        int p = base + k * (TPB * 4) + tid * 4;
        if (p + 3 < n_pix) {
            int4 v = *reinterpret_cast<const int4*>(pix + p);
            id[k*4+0] = v.x; id[k*4+1] = v.y; id[k*4+2] = v.z; id[k*4+3] = v.w;
        } else {
            for (int j = 0; j < 4; ++j) id[k*4+j] = (p + j < n_pix) ? pix[p + j] : -1;
        }
    }

    u32 c[PXT];
#pragma unroll
    for (int k = 0; k < PXT; ++k) c[k] = 0u;    // background stays black

    __syncthreads();                    // first slice ready

    for (int s = 0; s < NSLICE; ++s) {
        int ps = s + off; if (ps >= NSLICE) ps -= NSLICE;
        unsigned sbase = (unsigned)(ps * SLICE_E);
#pragma unroll
        for (int k = 0; k < PXT; ++k) {
            unsigned rel = (unsigned)id[k] - sbase;   // wraps huge for -1/out
            if (rel < (unsigned)SLICE_E) c[k] = (u32)buf[rel];
        }
        if (s + 1 < NSLICE) {
            int pn = ps + 1; if (pn >= NSLICE) pn -= NSLICE;
            __syncthreads();            // scan done -> buf free
            stage(pn);
            __syncthreads();            // stage drained -> buf valid
        }
    }

    if (cbuf) {
        // ---- split mode: store u16 colors, coalesced 8B/thread-group ----
#pragma unroll
        for (int k = 0; k < 4; ++k) {
            int p = base + k * (TPB * 4) + tid * 4;
            if (p + 3 < n_pix) {
                u32 w0 = c[k*4+0] | (c[k*4+1] << 16);
                u32 w1 = c[k*4+2] | (c[k*4+3] << 16);
                *reinterpret_cast<uint2*>(cbuf + p) = make_uint2(w0, w1);
            } else {
                for (int j = 0; j < 4; ++j)
                    if (p + j < n_pix) cbuf[p + j] = (u16)c[k*4+j];
            }
        }
    } else {
        // ---- fused fallback: decode + f32 stores (R15 epilogue) ----
#pragma unroll
        for (int k = 0; k < 4; ++k) {
            int p = base + k * (TPB * 4) + tid * 4;
            float v[12];
#pragma unroll
            for (int j = 0; j < 4; ++j) {
                u32 cc = c[k*4+j];
                v[j*3+0] = (float)((cc >> 11) & 31u) * (1.0f/31.0f);
                v[j*3+1] = (float)((cc >>  5) & 63u) * (1.0f/63.0f);
                v[j*3+2] = (float)( cc        & 31u) * (1.0f/31.0f);
            }
            if (p + 3 < n_pix) {
                float4* o = reinterpret_cast<float4*>(out + (size_t)p * 3);
                o[0] = make_float4(v[0], v[1], v[2],  v[3]);
                o[1] = make_float4(v[4], v[5], v[6],  v[7]);
                o[2] = make_float4(v[8], v[9], v[10], v[11]);
            } else {
                for (int j = 0; j < 4; ++j)
                    if (p + j < n_pix) {
                        out[(size_t)(p+j)*3+0] = v[j*3+0];
                        out[(size_t)(p+j)*3+1] = v[j*3+1];
                        out[(size_t)(p+j)*3+2] = v[j*3+2];
                    }
            }
        }
    }
}

// Kernel B: pure stream decode, fill-kernel-shaped (256 threads, 8 px/thread).
__global__ __launch_bounds__(256)
void decode_kernel(const u16* __restrict__ cbuf,
                   float*     __restrict__ out,
                   int n_pix) {
    int t  = blockIdx.x * blockDim.x + threadIdx.x;
    int p0 = t * 8;
    if (p0 >= n_pix) return;

    if (p0 + 7 < n_pix) {
        int4 raw = *reinterpret_cast<const int4*>(cbuf + p0);   // 8 x u16
        u32 w[4] = {(u32)raw.x, (u32)raw.y, (u32)raw.z, (u32)raw.w};
        float v[24];
#pragma unroll
        for (int h = 0; h < 4; ++h) {
#pragma unroll
            for (int g = 0; g < 2; ++g) {
                u32 cc = (w[h] >> (16 * g)) & 0xFFFFu;
                int j = h * 2 + g;
                v[j*3+0] = (float)((cc >> 11) & 31u) * (1.0f/31.0f);
                v[j*3+1] = (float)((cc >>  5) & 63u) * (1.0f/63.0f);
                v[j*3+2] = (float)( cc        & 31u) * (1.0f/31.0f);
            }
        }
        float4* o = reinterpret_cast<float4*>(out + (size_t)p0 * 3);  // p0*12B, 16B-aligned
        o[0] = make_float4(v[0],  v[1],  v[2],  v[3]);
        o[1] = make_float4(v[4],  v[5],  v[6],  v[7]);
        o[2] = make_float4(v[8],  v[9],  v[10], v[11]);
        o[3] = make_float4(v[12], v[13], v[14], v[15]);
        o[4] = make_float4(v[16], v[17], v[18], v[19]);
        o[5] = make_float4(v[20], v[21], v[22], v[23]);
    } else {
        for (int p = p0; p < n_pix; ++p) {
            u32 cc = (u32)cbuf[p];
            out[(size_t)p*3+0] = (float)((cc >> 11) & 31u) * (1.0f/31.0f);
            out[(size_t)p*3+1] = (float)((cc >>  5) & 63u) * (1.0f/63.0f);
            out[(size_t)p*3+2] = (float)( cc        & 31u) * (1.0f/31.0f);
        }
    }
}

extern "C" void kernel_launch(void* const* d_in, const int* in_sizes, int n_in,
                              void* d_out, int out_size, void* d_ws, size_t ws_size,
                              hipStream_t stream) {
    const float* verts = (const float*)d_in[0];   // [V,3] f32
    const int*   faces = (const int*)d_in[1];     // [F,3] i32
    const int*   pix   = (const int*)d_in[2];     // [B,H,W,1] i32
    float*       out   = (float*)d_out;           // [B,H,W,3] f32

    int F     = in_sizes[1] / 3;
    int n_pix = in_sizes[2];
    int Fpad  = NSLICE * SLICE_E;                 // 204800 >= F

    u16* tab = (u16*)d_ws;                        // [Fpad] RGB565, 400 KB
    const size_t CBUF_OFF = 512 * 1024;           // aligned offset for cbuf
    size_t need = CBUF_OFF + (size_t)n_pix * sizeof(u16);
    u16* cbuf = (ws_size >= need) ? (u16*)((char*)d_ws + CBUF_OFF) : nullptr;

    {
        int threads = 256;
        int blocks  = (Fpad + threads - 1) / threads;
        face_avg_565_kernel<<<blocks, threads, 0, stream>>>(verts, faces, tab, F, Fpad);
    }
    {
        int blocks = (n_pix + PPB - 1) / PPB;     // 512
        shade_kernel<<<blocks, TPB, 0, stream>>>(pix, tab, cbuf, out, n_pix);
    }
    if (cbuf) {
        int threads = 256;
        int blocks  = (n_pix / 8 + threads - 1) / threads;   // 4096
        decode_kernel<<<blocks, threads, 0, stream>>>(cbuf, out, n_pix);
    }
}

// Round 18
// 47.341 us; speedup vs baseline: 1.2816x; 1.2816x over previous
//
#include <hip/hip_runtime.h>

// FlatColorShader: LDS table scan with FULL-LDS double-buffer (2 x 80 KB =
// 160 KB), one block per CU, one barrier per slice, stage always in flight.
//
// Evidence trail:
//  R1-R5:  VMEM random gather capped ~0.2 lines/cy/CU (MSHR/L1-fill) -> LDS gather.
//  R6:     spills -> launch_bounds. R14: de-masked scan 6x LDS work, regressed.
//  R13/R15: best 2-block config (5 x 80 KB single-buf, parity stagger) = 47.1us.
//  R16:    in-block VMEM mix regressed (shared vmcnt + L1 contention).
//  R17:    SPLIT DATUM: scan machine with 1/6 store bytes still ~40us -> f32
//          stores were ~85% hidden; the cost is the scan machine (barriers +
//          stage exposure + 2-block PHASE-LOCKING: nothing forces anti-phase,
//          resource coupling makes co-resident blocks stage together).
//  R18:    eliminate the partner block: dbuf 2x80KB = exactly 160 KB (full CU
//          LDS, HW-supported per-WG), 1 block/CU, 256 blocks, PXT=32.
//          stage(s+1) issued into the idle buffer BEFORE scanning s -> stage
//          hidden under the scan; ONE barrier per slice (end barrier is also
//          the overwrite guard: lgkm-drained scans precede next stage).
//      RGB565 table (2 B/face), err 0.0161 < 0.0199 (validated R8-R17).

#define SLICE_E 40960        // u16 entries per slice = 80 KiB
#define NSLICE  5            // ceil(200000 / 40960)
#define TPB     1024
#define PXT     32           // pixels per thread
#define PPB     (TPB * PXT)  // 32768 px per block -> 256 blocks = 1/CU

typedef unsigned u32;
typedef unsigned short u16;

__global__ void face_avg_565_kernel(const float* __restrict__ verts,
                                    const int*   __restrict__ faces,
                                    u16*         __restrict__ tab,
                                    int F, int Fpad) {
    int f = blockIdx.x * blockDim.x + threadIdx.x;
    if (f >= Fpad) return;
    u32 packed = 0u;
    if (f < F) {
        int i0 = faces[3*f+0], i1 = faces[3*f+1], i2 = faces[3*f+2];
        const float s = 1.0f / 3.0f;
        float r = (verts[3*i0+0] + verts[3*i1+0] + verts[3*i2+0]) * s;
        float g = (verts[3*i0+1] + verts[3*i1+1] + verts[3*i2+1]) * s;
        float b = (verts[3*i0+2] + verts[3*i1+2] + verts[3*i2+2]) * s;
        u32 r5 = (u32)__float2int_rn(r * 31.0f);
        u32 g6 = (u32)__float2int_rn(g * 63.0f);
        u32 b5 = (u32)__float2int_rn(b * 31.0f);
        packed = (r5 << 11) | (g6 << 5) | b5;
    }
    tab[f] = (u16)packed;
}

__global__ __launch_bounds__(TPB, 4)
void shade_kernel(const int* __restrict__ pix,
                  const u16* __restrict__ tab,
                  float*     __restrict__ out,
                  int n_pix) {
    __shared__ u16 buf[2][SLICE_E];     // 2 x 80 KiB = 160 KiB (full CU LDS)
    const int tid  = threadIdx.x;
    const int lane = tid & 63;
    const int wave = tid >> 6;          // 0..15
    const int base = blockIdx.x * PPB;

    // stage one 80 KB slice into half h: 16 waves x 5 chunks x (64 lanes * 16B)
    auto stage = [&](int ss, int h) {
        const u16* g = tab + (size_t)ss * SLICE_E + wave * 2560 + lane * 8;
#pragma unroll
        for (int j = 0; j < 5; ++j) {
            __builtin_amdgcn_global_load_lds(
                (const __attribute__((address_space(1))) u32*)(g + j * 512),
                (__attribute__((address_space(3))) u32*)(&buf[h][wave * 2560 + j * 512]),
                16, 0, 0);
        }
    };

    stage(0, 0);                        // slice 0 in flight during id load

    // ---- load this thread's 32 pixel ids (8 x int4, coalesced) ----
    int id[PXT];
#pragma unroll
    for (int k = 0; k < 8; ++k) {
        int p = base + k * (TPB * 4) + tid * 4;
        if (p + 3 < n_pix) {
            int4 v = *reinterpret_cast<const int4*>(pix + p);
            id[k*4+0] = v.x; id[k*4+1] = v.y; id[k*4+2] = v.z; id[k*4+3] = v.w;
        } else {
            for (int j = 0; j < 4; ++j) id[k*4+j] = (p + j < n_pix) ? pix[p + j] : -1;
        }
    }

    u32 c[PXT];
#pragma unroll
    for (int k = 0; k < PXT; ++k) c[k] = 0u;    // background stays black

    __syncthreads();                    // drains vmcnt: slice 0 ready (ids too)

    for (int s = 0; s < NSLICE; ++s) {
        // issue next-slice stage into the idle buffer FIRST (hidden under scan).
        // Overwrite-safe: previous iteration's end-barrier followed lgkmcnt(0),
        // so all waves' scans of that buffer are complete.
        if (s + 1 < NSLICE) stage(s + 1, (s + 1) & 1);

        unsigned sbase = (unsigned)(s * SLICE_E);
        const u16* bc = buf[s & 1];
#pragma unroll
        for (int k = 0; k < PXT; ++k) {
            unsigned rel = (unsigned)id[k] - sbase;   // wraps huge for -1/out
            if (rel < (unsigned)SLICE_E) c[k] = (u32)bc[rel];
        }
        asm volatile("s_waitcnt lgkmcnt(0)" ::: "memory");   // scan reads in regs
        __builtin_amdgcn_sched_barrier(0);
        if (s + 1 < NSLICE) {
            asm volatile("s_waitcnt vmcnt(0)" ::: "memory"); // stage(s+1) done
            __builtin_amdgcn_sched_barrier(0);
            __builtin_amdgcn_s_barrier();   // ONE barrier/slice: buf[s+1] valid
        }
    }

    // ---- epilogue: decode RGB565 -> f32, coalesced float4 stores ----
#pragma unroll
    for (int k = 0; k < 8; ++k) {
        int p = base + k * (TPB * 4) + tid * 4;
        float v[12];
#pragma unroll
        for (int j = 0; j < 4; ++j) {
            u32 cc = c[k*4+j];
            v[j*3+0] = (float)((cc >> 11) & 31u) * (1.0f/31.0f);
            v[j*3+1] = (float)((cc >>  5) & 63u) * (1.0f/63.0f);
            v[j*3+2] = (float)( cc        & 31u) * (1.0f/31.0f);
        }
        if (p + 3 < n_pix) {
            float4* o = reinterpret_cast<float4*>(out + (size_t)p * 3);  // 16B-aligned
            o[0] = make_float4(v[0], v[1], v[2],  v[3]);
            o[1] = make_float4(v[4], v[5], v[6],  v[7]);
            o[2] = make_float4(v[8], v[9], v[10], v[11]);
        } else {
            for (int j = 0; j < 4; ++j)
                if (p + j < n_pix) {
                    out[(size_t)(p+j)*3+0] = v[j*3+0];
                    out[(size_t)(p+j)*3+1] = v[j*3+1];
                    out[(size_t)(p+j)*3+2] = v[j*3+2];
                }
        }
    }
}

extern "C" void kernel_launch(void* const* d_in, const int* in_sizes, int n_in,
                              void* d_out, int out_size, void* d_ws, size_t ws_size,
                              hipStream_t stream) {
    const float* verts = (const float*)d_in[0];   // [V,3] f32
    const int*   faces = (const int*)d_in[1];     // [F,3] i32
    const int*   pix   = (const int*)d_in[2];     // [B,H,W,1] i32
    float*       out   = (float*)d_out;           // [B,H,W,3] f32
    u16*         tab   = (u16*)d_ws;              // [Fpad] RGB565 (400 KB)

    int F     = in_sizes[1] / 3;
    int n_pix = in_sizes[2];
    int Fpad  = NSLICE * SLICE_E;                 // 204800 >= F

    {
        int threads = 256;
        int blocks  = (Fpad + threads - 1) / threads;
        face_avg_565_kernel<<<blocks, threads, 0, stream>>>(verts, faces, tab, F, Fpad);
    }
    {
        int blocks = (n_pix + PPB - 1) / PPB;     // 256
        shade_kernel<<<blocks, TPB, 0, stream>>>(pix, tab, out, n_pix);
    }
}